// Round 6
// baseline (310.450 us; speedup 1.0000x reference)
//
#include <hip/hip_runtime.h>
#include <hip/hip_bf16.h>
#include <stdint.h>
#include <stddef.h>

using bf16 = __hip_bfloat16;

typedef __attribute__((ext_vector_type(4))) float f32x4;
typedef __attribute__((ext_vector_type(16))) float f32x16;
typedef __attribute__((ext_vector_type(8))) short bf16x8;
typedef __attribute__((ext_vector_type(4))) unsigned short u16x4;

#define K_DIM 4096
#define M_ROWS 8192
#define BM 256
#define BN 256
#define BK 64
#define NT (K_DIM / BK)      // 64 K-tiles
#define MT2 (M_ROWS / BM)    // 32
#define NT2 (K_DIM / BN)     // 16

template<bool B> struct BC { static constexpr bool value = B; };

// ---------------------------------------------------------------------------
// Kernel 1: f32 -> bf16 conversion (vectorized, grid-stride)
// ---------------------------------------------------------------------------
__global__ void conv_bf16(const float* __restrict__ in, bf16* __restrict__ outb, int n4) {
  int idx = blockIdx.x * blockDim.x + threadIdx.x;
  int stride = gridDim.x * blockDim.x;
  for (int k = idx; k < n4; k += stride) {
    f32x4 v = ((const f32x4*)in)[k];
    bf16 tmp[4];
    tmp[0] = __float2bfloat16(v.x);
    tmp[1] = __float2bfloat16(v.y);
    tmp[2] = __float2bfloat16(v.z);
    tmp[3] = __float2bfloat16(v.w);
    ((u16x4*)outb)[k] = *(const u16x4*)tmp;
  }
}

// ---------------------------------------------------------------------------
// Kernel 2: build G^T in bf16 (verified round 1).
// ---------------------------------------------------------------------------
__global__ void build_gt(const float* __restrict__ core0, const float* __restrict__ core1,
                         bf16* __restrict__ GT) {
  int j = blockIdx.x >> 6;
  int i = blockIdx.x & 63;
  __shared__ float c0s[64][16];
  __shared__ float c1s[64][16];
  int t = threadIdx.x;
#pragma unroll
  for (int rep = 0; rep < 4; ++rep) {
    int idx = rep * 256 + t;
    int row = idx >> 4;
    int b = idx & 15;
    size_t base = ((size_t)(j * 64 + row) * 64 + i) * 16 + b;
    c1s[row][b] = core1[base];
    c0s[row][b] = core0[base];
  }
  __syncthreads();
  int x = t & 63;
  int ys = t >> 6;
  float r1[16];
#pragma unroll
  for (int b = 0; b < 16; ++b) r1[b] = c1s[x][b];
#pragma unroll
  for (int yy = 0; yy < 16; ++yy) {
    int y = ys * 16 + yy;
    float acc = 0.f;
#pragma unroll
    for (int b = 0; b < 16; ++b) acc += r1[b] * c0s[y][b];
    GT[((size_t)(y * 64 + i) << 12) + (size_t)(j * 64 + x)] = __float2bfloat16(acc);
  }
}

// ---------------------------------------------------------------------------
// Kernel 3: 256x256 / BK=64 / 8-wave / mfma_32x32x16. K-step software pipeline:
// per step, MFMA(set p) overlaps ds_reads into set p^1 (reg double-buffer).
// Staging one tile ahead into the other LDS buffer => 1 barrier + 1 vmcnt(0)
// per K-tile, no mid-tile hazards.
// ---------------------------------------------------------------------------
__device__ __forceinline__ void gload_lds16(const bf16* g, bf16* l) {
  __builtin_amdgcn_global_load_lds(
      (const __attribute__((address_space(1))) unsigned int*)(g),
      (__attribute__((address_space(3))) unsigned int*)(l),
      16, 0, 0);
}

#define BARRIER() __builtin_amdgcn_s_barrier()
#define SP1() __builtin_amdgcn_s_setprio(1)
#define SP0() __builtin_amdgcn_s_setprio(0)
#define VMCNT0() asm volatile("s_waitcnt vmcnt(0)" ::: "memory")

__global__ __launch_bounds__(512, 2)
void gemm_xg(const bf16* __restrict__ Xb, const bf16* __restrict__ GT,
             const float* __restrict__ bias, float* __restrict__ out) {
  __shared__ bf16 As[2][BM * BK];   // 2 x 32 KiB
  __shared__ bf16 Bs[2][BN * BK];   // 2 x 32 KiB

  // XCD-aware swizzle: nwg = 512, divisible by 8
  int bid = blockIdx.x;
  int sb = (bid & 7) * (MT2 * NT2 / 8) + (bid >> 3);
  int bm = sb >> 4;
  int bn = sb & 15;

  int t = threadIdx.x;
  int lane = t & 63;
  int wid = t >> 6;

  // ---- staging addressing (linear LDS dest, inverse-swizzled global src) ----
  int srow = t >> 3;                    // 0..63
  int scol = t & 7;                     // 16B slot
  int sxor = scol ^ (srow & 7);         // pre-swizzled global slot
  const bf16* gA0 = Xb + ((size_t)(bm * BM + srow) * K_DIM) + sxor * 8;
  const bf16* gB0 = GT + ((size_t)(bn * BN + srow) * K_DIM) + sxor * 8;
  int lbase = srow * BK + scol * 8;

  auto sA = [&](int buf, int h, int kt) {
    const bf16* g = gA0 + (size_t)(h * 128) * K_DIM + (size_t)kt * BK;
    bf16* l = &As[buf][h * 128 * BK + lbase];
    gload_lds16(g, l);
    gload_lds16(g + (size_t)64 * K_DIM, l + 64 * BK);
  };
  auto sB = [&](int buf, int h, int kt) {
    const bf16* g = gB0 + (size_t)(h * 128) * K_DIM + (size_t)kt * BK;
    bf16* l = &Bs[buf][h * 128 * BK + lbase];
    gload_lds16(g, l);
    gload_lds16(g + (size_t)64 * K_DIM, l + 64 * BK);
  };

  // ---- fragment addressing (32x32x16: row = lane&31, k-half = lane>>5) ----
  int wm = wid >> 2;        // 0..1
  int wn = wid & 3;         // 0..3
  int l31 = lane & 31;
  int lh = lane >> 5;       // 0..1
  int x7 = l31 & 7;
  int abase = (wm * 128 + l31) * BK;   // + mi*32*64
  int bbase = (wn * 64 + l31) * BK;    // + ni*32*64
  // per-kstep swizzled slot byte... element offsets
  int so[4];
#pragma unroll
  for (int s = 0; s < 4; ++s) so[s] = (((2 * s + lh) ^ x7) << 3);

  f32x16 acc[4][2] = {};
  bf16x8 a0[4], b0[2], a1[4], b1[2];

  auto readset = [&](bf16x8 (&af)[4], bf16x8 (&bv)[2],
                     const bf16* Ab, const bf16* Bb, int s) {
    int sofs = so[s];
#pragma unroll
    for (int mi = 0; mi < 4; ++mi)
      af[mi] = *(const bf16x8*)&Ab[abase + mi * 2048 + sofs];
#pragma unroll
    for (int ni = 0; ni < 2; ++ni)
      bv[ni] = *(const bf16x8*)&Bb[bbase + ni * 2048 + sofs];
  };
  auto mstep = [&](bf16x8 (&af)[4], bf16x8 (&bv)[2]) {
    SP1();
#pragma unroll
    for (int mi = 0; mi < 4; ++mi)
#pragma unroll
      for (int ni = 0; ni < 2; ++ni)
        acc[mi][ni] = __builtin_amdgcn_mfma_f32_32x32x16_bf16(
            af[mi], bv[ni], acc[mi][ni], 0, 0, 0);
    SP0();
  };

  const bf16* A0 = &As[0][0];
  const bf16* B0 = &Bs[0][0];
  const bf16* A1 = &As[1][0];
  const bf16* B1 = &Bs[1][0];

  // ---- per-tile: 4 k-steps, frag ping-pong; stage t+1 into other buffer ----
  auto tile = [&](int kt, const bf16* Ac, const bf16* Bc, int obuf, auto lastc) {
    constexpr bool LAST = decltype(lastc)::value;
    // step 0: MFMA set0 || read set1(k1) || stage A(t+1)
    if (!LAST) { sA(obuf, 0, kt + 1); sA(obuf, 1, kt + 1); }
    readset(a1, b1, Ac, Bc, 1);
    mstep(a0, b0);
    // step 1: MFMA set1 || read set0(k2) || stage B(t+1)
    if (!LAST) { sB(obuf, 0, kt + 1); sB(obuf, 1, kt + 1); }
    readset(a0, b0, Ac, Bc, 2);
    mstep(a1, b1);
    // step 2: MFMA set0 || read set1(k3)
    readset(a1, b1, Ac, Bc, 3);
    mstep(a0, b0);
    // step 3: MFMA set1; drain stages; boundary barrier
    VMCNT0();
    mstep(a1, b1);
    BARRIER();
  };

  // ---- prologue: stage tile0, drain, pre-read step0 frags ----
  sA(0, 0, 0); sA(0, 1, 0);
  sB(0, 0, 0); sB(0, 1, 0);
  VMCNT0();
  BARRIER();
  readset(a0, b0, A0, B0, 0);

#pragma unroll 1
  for (int i = 0; i < NT / 2 - 1; ++i) {
    tile(2 * i, A0, B0, 1, BC<false>{});
    readset(a0, b0, A1, B1, 0);
    tile(2 * i + 1, A1, B1, 0, BC<false>{});
    readset(a0, b0, A0, B0, 0);
  }
  tile(NT - 2, A0, B0, 1, BC<false>{});
  readset(a0, b0, A1, B1, 0);
  tile(NT - 1, A1, B1, 0, BC<true>{});

  // ---- epilogue: 32x32 C/D layout: col=lane&31, row=(r&3)+8*(r>>2)+4*lh ----
  int colbase = bn * BN + wn * 64 + l31;
  int rowbase = bm * BM + wm * 128 + 4 * lh;
#pragma unroll
  for (int ni = 0; ni < 2; ++ni) {
    int col = colbase + ni * 32;
    float bv = bias[col];
#pragma unroll
    for (int mi = 0; mi < 4; ++mi) {
#pragma unroll
      for (int r = 0; r < 16; ++r) {
        int row = rowbase + mi * 32 + (r & 3) + 8 * (r >> 2);
        out[(size_t)row * K_DIM + col] = acc[mi][ni][r] + bv;
      }
    }
  }
}

// ---------------------------------------------------------------------------
extern "C" void kernel_launch(void* const* d_in, const int* in_sizes, int n_in,
                              void* d_out, int out_size, void* d_ws, size_t ws_size,
                              hipStream_t stream) {
  const float* x     = (const float*)d_in[0];
  const float* core0 = (const float*)d_in[1];
  const float* core1 = (const float*)d_in[2];
  const float* bias  = (const float*)d_in[3];
  float* out = (float*)d_out;

  bf16* Xb = (bf16*)d_ws;
  bf16* GT = (bf16*)((char*)d_ws + (size_t)M_ROWS * K_DIM * sizeof(bf16));

  conv_bf16<<<2048, 256, 0, stream>>>(x, Xb, (M_ROWS * K_DIM) / 4);
  build_gt<<<4096, 256, 0, stream>>>(core0, core1, GT);
  gemm_xg<<<MT2 * NT2, 512, 0, stream>>>(Xb, GT, bias, out);
}